// Round 1
// baseline (920.224 us; speedup 1.0000x reference)
//
#include <hip/hip_runtime.h>
#include <stdint.h>

#define QEPS 1e-8f

// ws layout: [0]=absmax bits of x (uint), [1]=absmax bits of W (uint),
//            [2]=int max |v| of conv accumulator, [3]=pad.
// int16 conv accumulator array at ws+256 (if ws big enough), else float v in d_out.

__global__ void k_init(unsigned int* s) {
  if (threadIdx.x < 4) s[threadIdx.x] = 0u;
}

__global__ __launch_bounds__(256) void k_absmax(
    const float4* __restrict__ x, int n4,
    const float* __restrict__ W, int nw,
    unsigned int* __restrict__ s) {
  __shared__ unsigned int red[256];
  const int t = threadIdx.x;
  unsigned int m = 0u;
  const int i = blockIdx.x * 256 + t;
  if (i < n4) {
    float4 v = x[i];
    m =        __float_as_uint(v.x) & 0x7fffffffu;
    m = max(m, __float_as_uint(v.y) & 0x7fffffffu);
    m = max(m, __float_as_uint(v.z) & 0x7fffffffu);
    m = max(m, __float_as_uint(v.w) & 0x7fffffffu);
  }
  red[t] = m;
  __syncthreads();
  for (int off = 128; off > 0; off >>= 1) {
    if (t < off) red[t] = max(red[t], red[t + off]);
    __syncthreads();
  }
  if (t == 0) atomicMax(&s[0], red[0]);

  if (blockIdx.x == 0) {
    unsigned int mw = 0u;
    for (int j = t; j < nw; j += 256)
      mw = max(mw, __float_as_uint(W[j]) & 0x7fffffffu);
    __syncthreads();
    red[t] = mw;
    __syncthreads();
    for (int off = 128; off > 0; off >>= 1) {
      if (t < off) red[t] = max(red[t], red[t + off]);
      __syncthreads();
    }
    if (t == 0) atomicMax(&s[1], red[0]);
  }
}

// Conv: N=16, C=3, H=W=224, OC=128, K=3, OH=OW=222, VALID, stride 1.
// Block: 256 threads = 16 ow-threads x 16 oc-threads. Per-thread tile: 4 ow x 8 oc.
// Block tile: 64 ow x 128 oc for one (n, oh). Grid: (4 ow-tiles, 222 oh, 16 n).
template<bool I16>
__global__ __launch_bounds__(256) void k_conv(
    const float* __restrict__ x, const float* __restrict__ W,
    const float* __restrict__ b, void* __restrict__ vout,
    const unsigned int* __restrict__ s, int* __restrict__ vmax) {
  __shared__ __align__(16) float wl[27][128];   // [k=c*9+kh*3+kw][oc], integer values
  __shared__ __align__(16) float xl[3][3][72];  // [c][kh][col], integer values
  __shared__ int red[256];

  const int t = threadIdx.x;
  const int ow0 = blockIdx.x * 64;
  const int oh = blockIdx.y;
  const int n = blockIdx.z;

  const float s_in = fmaxf(__uint_as_float(s[0]) / 127.0f, QEPS);
  const float s_w  = fmaxf(__uint_as_float(s[1]) / 7.0f,  QEPS);

  // stage quantized W (as small-int floats). o = lane, contiguous LDS writes.
  {
    const int o = t & 127;
    for (int k = (t >> 7); k < 27; k += 2) {
      float q = rintf(W[o * 27 + k] / s_w);
      wl[k][o] = fminf(fmaxf(q, -7.0f), 7.0f);
    }
  }
  // stage quantized x slab: rows oh..oh+2, 3 channels, cols ow0..ow0+67 (zero-pad OOB)
  for (int i = t; i < 9 * 68; i += 256) {
    const int row = i / 68;
    const int col = i - row * 68;
    const int c = row / 3, kh = row - c * 3;
    const int gcol = ow0 + col;
    float q = 0.0f;
    if (gcol < 224) {
      const float xv = x[((n * 3 + c) * 224 + (oh + kh)) * 224 + gcol];
      q = fminf(fmaxf(rintf(xv / s_in), -128.0f), 127.0f);
    }
    xl[c][kh][col] = q;
  }
  __syncthreads();

  const int lane = t & 15;        // ow group
  const int oc0 = (t >> 4) * 8;   // oc base
  const int lane4 = lane * 4;

  float acc[4][8];
  #pragma unroll
  for (int r = 0; r < 4; ++r)
    #pragma unroll
    for (int cc = 0; cc < 8; ++cc) acc[r][cc] = 0.0f;

  #pragma unroll
  for (int c = 0; c < 3; ++c) {
    #pragma unroll
    for (int kh = 0; kh < 3; ++kh) {
      const float4 xa = *(const float4*)&xl[c][kh][lane4];
      const float4 xb = *(const float4*)&xl[c][kh][lane4 + 4];
      const float xv[8] = {xa.x, xa.y, xa.z, xa.w, xb.x, xb.y, xb.z, xb.w};
      #pragma unroll
      for (int kw = 0; kw < 3; ++kw) {
        const float* wp = &wl[(c * 3 + kh) * 3 + kw][oc0];
        const float4 wa = *(const float4*)wp;
        const float4 wb = *(const float4*)(wp + 4);
        const float wv[8] = {wa.x, wa.y, wa.z, wa.w, wb.x, wb.y, wb.z, wb.w};
        #pragma unroll
        for (int r = 0; r < 4; ++r) {
          #pragma unroll
          for (int cc = 0; cc < 8; ++cc)
            acc[r][cc] += xv[r + kw] * wv[cc];
        }
      }
    }
  }

  const float s_b = s_in * s_w;
  float qb[8];
  #pragma unroll
  for (int cc = 0; cc < 8; ++cc) qb[cc] = rintf(b[oc0 + cc] / s_b);

  const int nvalid = min(4, 222 - (ow0 + lane4));  // may be <= 0 on last tile
  int mymax = 0;
  #pragma unroll
  for (int cc = 0; cc < 8; ++cc) {
    float v[4];
    #pragma unroll
    for (int r = 0; r < 4; ++r) v[r] = acc[r][cc] + qb[cc];
    #pragma unroll
    for (int r = 0; r < 4; ++r) {
      if (r < nvalid) {
        const int iv = (int)v[r];
        mymax = max(mymax, iv < 0 ? -iv : iv);
      }
    }
    const int base = ((n * 128 + oc0 + cc) * 222 + oh) * 222 + ow0 + lane4;
    if (I16) {
      short* sp = (short*)vout;
      if (nvalid >= 4) {
        *(short2*)&sp[base]     = make_short2((short)(int)v[0], (short)(int)v[1]);
        *(short2*)&sp[base + 2] = make_short2((short)(int)v[2], (short)(int)v[3]);
      } else {
        for (int r = 0; r < nvalid; ++r) sp[base + r] = (short)(int)v[r];
      }
    } else {
      float* fp = (float*)vout;
      if (nvalid >= 4) {
        *(float2*)&fp[base]     = make_float2(v[0], v[1]);
        *(float2*)&fp[base + 2] = make_float2(v[2], v[3]);
      } else {
        for (int r = 0; r < nvalid; ++r) fp[base + r] = v[r];
      }
    }
  }

  red[t] = mymax;
  __syncthreads();
  for (int off = 128; off > 0; off >>= 1) {
    if (t < off) red[t] = max(red[t], red[t + off]);
    __syncthreads();
  }
  if (t == 0) atomicMax(vmax, red[0]);
}

// Final fake-quant of output. 8 elements/thread. NOTE: no __restrict__ on
// vin/out — in the fallback path they alias (in-place), same-thread RMW only.
template<bool I16>
__global__ __launch_bounds__(256) void k_quant(
    const void* vin, float* out,
    const unsigned int* __restrict__ s, const int* __restrict__ vmax, int n8) {
  const int i = blockIdx.x * 256 + threadIdx.x;
  if (i >= n8) return;
  const float s_in = fmaxf(__uint_as_float(s[0]) / 127.0f, QEPS);
  const float s_w  = fmaxf(__uint_as_float(s[1]) / 7.0f,  QEPS);
  const float s_b = s_in * s_w;
  const float ymax = s_b * (float)(*vmax);
  const float s_out = fmaxf(ymax / 127.0f, QEPS);

  float v[8];
  if (I16) {
    const int4 w = ((const int4*)vin)[i];
    v[0] = (float)(short)(w.x & 0xffff); v[1] = (float)(short)(w.x >> 16);
    v[2] = (float)(short)(w.y & 0xffff); v[3] = (float)(short)(w.y >> 16);
    v[4] = (float)(short)(w.z & 0xffff); v[5] = (float)(short)(w.z >> 16);
    v[6] = (float)(short)(w.w & 0xffff); v[7] = (float)(short)(w.w >> 16);
  } else {
    const float4 a = ((const float4*)vin)[2 * i];
    const float4 bb = ((const float4*)vin)[2 * i + 1];
    v[0] = a.x;  v[1] = a.y;  v[2] = a.z;  v[3] = a.w;
    v[4] = bb.x; v[5] = bb.y; v[6] = bb.z; v[7] = bb.w;
  }
  float o[8];
  #pragma unroll
  for (int j = 0; j < 8; ++j) {
    const float y = s_b * v[j];
    float q = rintf(y / s_out);
    q = fminf(fmaxf(q, -128.0f), 127.0f);
    o[j] = q * s_out;
  }
  ((float4*)out)[2 * i]     = make_float4(o[0], o[1], o[2], o[3]);
  ((float4*)out)[2 * i + 1] = make_float4(o[4], o[5], o[6], o[7]);
}

extern "C" void kernel_launch(void* const* d_in, const int* in_sizes, int n_in,
                              void* d_out, int out_size, void* d_ws, size_t ws_size,
                              hipStream_t stream) {
  const float* x = (const float*)d_in[0];
  const float* W = (const float*)d_in[1];
  const float* b = (const float*)d_in[2];
  float* out = (float*)d_out;

  unsigned int* s = (unsigned int*)d_ws;
  int* vmax = ((int*)d_ws) + 2;

  const int n_out = out_size;  // 100,925,568
  const bool i16 = ws_size >= (size_t)256 + 2ull * (size_t)n_out;
  void* vbuf = i16 ? (void*)((char*)d_ws + 256) : (void*)d_out;

  k_init<<<1, 64, 0, stream>>>(s);

  const int n4 = in_sizes[0] / 4;  // 602,112
  k_absmax<<<(n4 + 255) / 256, 256, 0, stream>>>(
      (const float4*)x, n4, W, in_sizes[1], s);

  dim3 grid(4, 222, 16);
  if (i16) k_conv<true ><<<grid, 256, 0, stream>>>(x, W, b, vbuf, s, vmax);
  else     k_conv<false><<<grid, 256, 0, stream>>>(x, W, b, vbuf, s, vmax);

  const int n8 = n_out / 8;  // 12,615,696
  if (i16) k_quant<true ><<<(n8 + 255) / 256, 256, 0, stream>>>(vbuf, out, s, vmax, n8);
  else     k_quant<false><<<(n8 + 255) / 256, 256, 0, stream>>>(vbuf, out, s, vmax, n8);
}

// Round 2
// 634.519 us; speedup vs baseline: 1.4503x; 1.4503x over previous
//
#include <hip/hip_runtime.h>
#include <stdint.h>

#define QEPS 1e-8f

// s (in d_ws): [0]=absmax bits of x, [1]=absmax bits of W, [2]=absmax bits of conv accum (float>=0)

__global__ void k_init(unsigned int* s) { if (threadIdx.x < 4) s[threadIdx.x] = 0u; }

__global__ __launch_bounds__(256) void k_absmax(
    const float4* __restrict__ x, int n4,
    const float* __restrict__ W, int nw,
    unsigned int* __restrict__ s) {
  __shared__ unsigned int red[256];
  const int t = threadIdx.x;
  unsigned int m = 0u;
  const int i = blockIdx.x * 256 + t;
  if (i < n4) {
    float4 v = x[i];
    m =        __float_as_uint(v.x) & 0x7fffffffu;
    m = max(m, __float_as_uint(v.y) & 0x7fffffffu);
    m = max(m, __float_as_uint(v.z) & 0x7fffffffu);
    m = max(m, __float_as_uint(v.w) & 0x7fffffffu);
  }
  red[t] = m;
  __syncthreads();
  for (int off = 128; off > 0; off >>= 1) {
    if (t < off) red[t] = max(red[t], red[t + off]);
    __syncthreads();
  }
  if (t == 0) atomicMax(&s[0], red[0]);

  if (blockIdx.x == 0) {
    unsigned int mw = 0u;
    for (int j = t; j < nw; j += 256)
      mw = max(mw, __float_as_uint(W[j]) & 0x7fffffffu);
    __syncthreads();
    red[t] = mw;
    __syncthreads();
    for (int off = 128; off > 0; off >>= 1) {
      if (t < off) red[t] = max(red[t], red[t + off]);
      __syncthreads();
    }
    if (t == 0) atomicMax(&s[1], red[0]);
  }
}

// Conv: N=16,C=3,H=W=224,OC=128,K=3 -> OH=OW=222, exact small-int arithmetic in fp32.
// Block: 256 thr = 16 ow-lanes x 16 oc-groups; per-thread 8 ow x 8 oc (acc=64).
// Tiles: owt(2, 128-wide) x n(16) x oh(222) = 7104 = 1776 blocks x 4-tile loop.
// W quantized into LDS ONCE per block. PASS 0: |v| max only (no stores).
// PASS 1: recompute conv, fake-quant, store NCHW f32.
template<int PASS>
__global__ __launch_bounds__(256, 3) void k_conv(
    const float* __restrict__ x, const float* __restrict__ W,
    const float* __restrict__ b, float* __restrict__ out,
    unsigned int* __restrict__ s) {
  __shared__ __align__(16) float wl[27][128];   // [tap=ck*3+kw][oc]
  __shared__ __align__(16) float xl[9][132];    // [ck=c*3+kh][col]
  __shared__ float redf[256];

  const int t = threadIdx.x;
  const int lane = t & 15;
  const int oc0 = (t >> 4) * 8;

  const float s_in = fmaxf(__uint_as_float(s[0]) / 127.0f, QEPS);
  const float s_w  = fmaxf(__uint_as_float(s[1]) / 7.0f,  QEPS);
  const float s_b  = s_in * s_w;

  float s_out = 1.0f, h = 1.0f;
  if (PASS == 1) {
    const float vmax = __uint_as_float(s[2]);
    s_out = fmaxf((s_b * vmax) / 127.0f, QEPS);
    h = s_b / s_out;   // q = rint(v*h), one step off at worst vs per-elem divide
  }

  // stage quantized W once per block (coalesced global reads)
  for (int i = t; i < 3456; i += 256) {
    const int o = i / 27;
    const int k = i - o * 27;
    float q = rintf(W[i] / s_w);
    wl[k][o] = fminf(fmaxf(q, -7.0f), 7.0f);
  }

  float qb[8];
  #pragma unroll
  for (int cc = 0; cc < 8; ++cc)
    qb[cc] = rintf(b[oc0 + cc] / s_b);

  float vmax_local = 0.0f;

  for (int it = 0; it < 4; ++it) {
    const int tile = blockIdx.x + it * 1776;
    const int owt = tile & 1;
    const int r2 = tile >> 1;
    const int n  = r2 & 15;
    const int oh = r2 >> 4;
    const int ow0 = owt * 128;

    // stage quantized x slab: 9 rows (c,kh) x 132 cols (cols ow0..ow0+131, 0-pad OOB)
    for (int i = t; i < 9 * 132; i += 256) {
      const int row = i / 132;
      const int col = i - row * 132;
      const int c  = row / 3;
      const int kh = row - c * 3;
      const int gcol = ow0 + col;
      float q = 0.0f;
      if (gcol < 224) {
        const float xv = x[((n * 3 + c) * 224 + (oh + kh)) * 224 + gcol];
        q = fminf(fmaxf(rintf(xv / s_in), -128.0f), 127.0f);
      }
      xl[row][col] = q;
    }
    __syncthreads();

    float acc[8][8];
    #pragma unroll
    for (int r = 0; r < 8; ++r)
      #pragma unroll
      for (int cc = 0; cc < 8; ++cc) acc[r][cc] = 0.0f;

    #pragma unroll 1
    for (int ck = 0; ck < 9; ++ck) {
      const float* xr = &xl[ck][lane * 8];
      const float4 a0 = *(const float4*)xr;
      const float4 a1 = *(const float4*)(xr + 4);
      const float4 a2 = *(const float4*)(xr + 8);
      const float xw[12] = {a0.x, a0.y, a0.z, a0.w, a1.x, a1.y, a1.z, a1.w,
                            a2.x, a2.y, a2.z, a2.w};
      #pragma unroll
      for (int kw = 0; kw < 3; ++kw) {
        const float* wp = &wl[ck * 3 + kw][oc0];
        const float4 w0 = *(const float4*)wp;
        const float4 w1 = *(const float4*)(wp + 4);
        const float wv[8] = {w0.x, w0.y, w0.z, w0.w, w1.x, w1.y, w1.z, w1.w};
        #pragma unroll
        for (int r = 0; r < 8; ++r) {
          #pragma unroll
          for (int cc = 0; cc < 8; ++cc)
            acc[r][cc] += xw[r + kw] * wv[cc];
        }
      }
    }

    const int owbase = ow0 + lane * 8;
    const int nv = min(8, 222 - owbase);  // can be <= 0 on the ragged tile

    if (PASS == 0) {
      if (nv > 0) {
        #pragma unroll
        for (int r = 0; r < 8; ++r) {
          if (r < nv) {
            #pragma unroll
            for (int cc = 0; cc < 8; ++cc)
              vmax_local = fmaxf(vmax_local, fabsf(acc[r][cc] + qb[cc]));
          }
        }
      }
    } else {
      if (nv > 0) {
        #pragma unroll
        for (int cc = 0; cc < 8; ++cc) {
          float o8[8];
          #pragma unroll
          for (int r = 0; r < 8; ++r) {
            float q = rintf((acc[r][cc] + qb[cc]) * h);
            q = fminf(fmaxf(q, -128.0f), 127.0f);
            o8[r] = q * s_out;
          }
          float* po = out + (((n * 128 + oc0 + cc) * 222 + oh) * 222 + owbase);
          if (nv == 8) {
            if ((oh & 1) == 0) {  // 16B-aligned rows (wave-uniform branch)
              *(float4*)po       = make_float4(o8[0], o8[1], o8[2], o8[3]);
              *(float4*)(po + 4) = make_float4(o8[4], o8[5], o8[6], o8[7]);
            } else {
              *(float2*)po       = make_float2(o8[0], o8[1]);
              *(float2*)(po + 2) = make_float2(o8[2], o8[3]);
              *(float2*)(po + 4) = make_float2(o8[4], o8[5]);
              *(float2*)(po + 6) = make_float2(o8[6], o8[7]);
            }
          } else {
            for (int r = 0; r < nv; ++r) po[r] = o8[r];
          }
        }
      }
    }
    __syncthreads();
  }

  if (PASS == 0) {
    redf[t] = vmax_local;
    __syncthreads();
    for (int off = 128; off > 0; off >>= 1) {
      if (t < off) redf[t] = fmaxf(redf[t], redf[t + off]);
      __syncthreads();
    }
    if (t == 0) atomicMax(&s[2], __float_as_uint(redf[0]));
  }
}

extern "C" void kernel_launch(void* const* d_in, const int* in_sizes, int n_in,
                              void* d_out, int out_size, void* d_ws, size_t ws_size,
                              hipStream_t stream) {
  const float* x = (const float*)d_in[0];
  const float* W = (const float*)d_in[1];
  const float* b = (const float*)d_in[2];
  float* out = (float*)d_out;
  unsigned int* s = (unsigned int*)d_ws;

  k_init<<<1, 64, 0, stream>>>(s);

  const int n4 = in_sizes[0] / 4;  // 602,112
  k_absmax<<<(n4 + 255) / 256, 256, 0, stream>>>(
      (const float4*)x, n4, W, in_sizes[1], s);

  k_conv<0><<<1776, 256, 0, stream>>>(x, W, b, out, s);
  k_conv<1><<<1776, 256, 0, stream>>>(x, W, b, out, s);
}